// Round 1
// baseline (325.845 us; speedup 1.0000x reference)
//
#include <hip/hip_runtime.h>

#define B_    8
#define CIN_  28
#define COUT_ 28
#define H_    256
#define W_    256
#define DG_   7
#define KH_   7
#define CPG_  4
#define HW_   (H_*W_)

// ---- prep: fold stage-2 (1x7 conv w_t,b_t) and stage-3 (group mix w_m,b_m)
// into a single effective 1x7 conv:  w_eff[o',c,k], b_eff[o'].
// final ch o' = f*4+cc :  out3[o'] = sum_g w_m[f,g]*(conv(out1,w_t)[g*4+cc]+b_t[g*4+cc]) + b_m[f]
__global__ void prep_weff(const float* __restrict__ w_t, const float* __restrict__ b_t,
                          const float* __restrict__ w_m, const float* __restrict__ b_m,
                          float* __restrict__ weff, float* __restrict__ beff) {
  int idx = blockIdx.x * blockDim.x + threadIdx.x;
  if (idx < COUT_ * COUT_ * 7) {
    int k  = idx % 7;
    int c  = (idx / 7) % COUT_;
    int op = idx / (7 * COUT_);
    int f = op >> 2, cc = op & 3;
    float s = 0.f;
#pragma unroll
    for (int g = 0; g < DG_; ++g)
      s += w_m[f * 7 + g] * w_t[((g * 4 + cc) * COUT_ + c) * 7 + k];
    weff[idx] = s;
  }
  if (idx < COUT_) {
    int f = idx >> 2, cc = idx & 3;
    float s = b_m[f];
#pragma unroll
    for (int g = 0; g < DG_; ++g) s += w_m[f * 7 + g] * b_t[g * 4 + cc];
    beff[idx] = s;
  }
}

// ---- fused kernel: one block per (b,h) row; thread = w.
// Stage 1: harmonic-sampled height conv -> acc[28] -> LDS row tile (with W halo)
// Stage 2: 1x7 conv along W with w_eff -> d_out
__global__ __launch_bounds__(256)
void harmonic_fused(const float* __restrict__ x, const float* __restrict__ wr,
                    const float* __restrict__ bias, const float* __restrict__ weff,
                    const float* __restrict__ beff, float* __restrict__ out) {
  __shared__ float tile[COUT_][W_ + 6];

  const int b = blockIdx.x >> 8;     // /H_
  const int h = blockIdx.x & 255;    // %H_
  const int w = threadIdx.x;

  float acc[COUT_];
#pragma unroll
  for (int o = 0; o < COUT_; ++o) acc[o] = bias[o];

  const float* xb = x + (size_t)b * CIN_ * HW_ + w;

  for (int g = 0; g < DG_; ++g) {
#pragma unroll
    for (int i = 0; i < KH_; ++i) {
      // replicate reference fp32 op order exactly:
      // off = (-i + (h+1)/(g+1)*(i+1)) - (h+1);  yp = ((h-3)+i) + off
      float t   = ((float)(h + 1) / (float)(g + 1)) * (float)(i + 1);
      float off = ((float)(-i) + t) - (float)(h + 1);
      float yp  = (((float)h - 3.0f) + (float)i) + off;
      float y0f = floorf(yp);
      float fy  = yp - y0f;
      int y0i = (int)y0f;
      int y1i = y0i + 1;
      const bool ok0 = (y0i >= 0) && (y0i <= H_ - 1);
      const bool ok1 = (y1i >= 0) && (y1i <= H_ - 1);
      if (!ok0 && !ok1) continue;          // wave-uniform skip
      float a0 = ok0 ? (1.0f - fy) : 0.0f;
      float a1 = ok1 ? fy : 0.0f;
      int y0c = y0i < 0 ? 0 : (y0i > H_ - 1 ? H_ - 1 : y0i);
      int y1c = y1i < 0 ? 0 : (y1i > H_ - 1 ? H_ - 1 : y1i);

      const float* p0 = xb + ((size_t)(g * CPG_) * H_ + y0c) * W_;
      const float* p1 = xb + ((size_t)(g * CPG_) * H_ + y1c) * W_;
      float s0 = a0 * p0[0 * HW_] + a1 * p1[0 * HW_];
      float s1 = a0 * p0[1 * HW_] + a1 * p1[1 * HW_];
      float s2 = a0 * p0[2 * HW_] + a1 * p1[2 * HW_];
      float s3 = a0 * p0[3 * HW_] + a1 * p1[3 * HW_];

      // weight[o, g*4+c, i] at flat o*196 + (g*4+c)*7 + i  (wave-uniform -> s_load)
      const float* wgi = wr + (g * CPG_) * KH_ + i;
#pragma unroll
      for (int o = 0; o < COUT_; ++o) {
        float a = acc[o];
        a += s0 * wgi[o * (CIN_ * KH_) + 0 * KH_];
        a += s1 * wgi[o * (CIN_ * KH_) + 1 * KH_];
        a += s2 * wgi[o * (CIN_ * KH_) + 2 * KH_];
        a += s3 * wgi[o * (CIN_ * KH_) + 3 * KH_];
        acc[o] = a;
      }
    }
  }

  // stash stage-1 row in LDS with zero halo (W padding of 3 each side)
  if (w < COUT_) {
#pragma unroll
    for (int j = 0; j < 3; ++j) { tile[w][j] = 0.f; tile[w][W_ + 3 + j] = 0.f; }
  }
#pragma unroll
  for (int o = 0; o < COUT_; ++o) tile[o][w + 3] = acc[o];
  __syncthreads();

  float acc2[COUT_];
#pragma unroll
  for (int o = 0; o < COUT_; ++o) acc2[o] = beff[o];

  for (int c = 0; c < COUT_; ++c) {
    float v0 = tile[c][w + 0];
    float v1 = tile[c][w + 1];
    float v2 = tile[c][w + 2];
    float v3 = tile[c][w + 3];
    float v4 = tile[c][w + 4];
    float v5 = tile[c][w + 5];
    float v6 = tile[c][w + 6];
    const float* wc = weff + c * 7;      // weff[o*196 + c*7 + k]
#pragma unroll
    for (int o = 0; o < COUT_; ++o) {
      const float* q = wc + o * (COUT_ * 7);
      float a = acc2[o];
      a += v0 * q[0]; a += v1 * q[1]; a += v2 * q[2]; a += v3 * q[3];
      a += v4 * q[4]; a += v5 * q[5]; a += v6 * q[6];
      acc2[o] = a;
    }
  }

  float* ob = out + (size_t)b * COUT_ * HW_ + (size_t)h * W_ + w;
#pragma unroll
  for (int o = 0; o < COUT_; ++o) ob[o * HW_] = acc2[o];
}

extern "C" void kernel_launch(void* const* d_in, const int* in_sizes, int n_in,
                              void* d_out, int out_size, void* d_ws, size_t ws_size,
                              hipStream_t stream) {
  const float* x      = (const float*)d_in[0];
  const float* weight = (const float*)d_in[1];
  const float* bias   = (const float*)d_in[2];
  const float* w_t    = (const float*)d_in[3];
  const float* b_t    = (const float*)d_in[4];
  const float* w_m    = (const float*)d_in[5];
  const float* b_m    = (const float*)d_in[6];
  float* out  = (float*)d_out;

  float* weff = (float*)d_ws;        // 28*28*7 = 5488 floats
  float* beff = weff + COUT_ * COUT_ * 7;   // 28 floats

  prep_weff<<<22, 256, 0, stream>>>(w_t, b_t, w_m, b_m, weff, beff);
  harmonic_fused<<<B_ * H_, 256, 0, stream>>>(x, weight, bias, weff, beff, out);
}

// Round 2
// 181.683 us; speedup vs baseline: 1.7935x; 1.7935x over previous
//
#include <hip/hip_runtime.h>
#include <hip/hip_bf16.h>

#define B_    8
#define CIN_  28
#define COUT_ 28
#define H_    256
#define W_    256
#define DG_   7
#define KH_   7
#define CPG_  4
#define HW_   (H_*W_)

typedef short short8 __attribute__((ext_vector_type(8)));
typedef short short4v __attribute__((ext_vector_type(4)));
typedef float f32x4 __attribute__((ext_vector_type(4)));

__device__ __forceinline__ short f2bf(float f) {
  __hip_bfloat16 h = __float2bfloat16(f);   // RNE
  return *reinterpret_cast<short*>(&h);
}

// ---------------------------------------------------------------------------
// prep: pack stage-1 weights (A1) and folded stage-2/3 weights (A2) into
// MFMA fragment-linear order, plus padded bias vectors.
//   A1[((mt*7+g)*64+lane)*8+j] = W1[o=mt*16+(lane&15)][k1=g*32+(lane>>4)*8+j]
//     where k1%32 = i*4+c  ->  weight[o][(g*4+c)][i]
//   A2[((mt*7+ks)*64+lane)*8+j] = weff[o][c=(lane>>4)*8+j][k=ks]
//     weff[o][c][k] = sum_g w_m[o>>2][g] * w_t[(g*4+(o&3))][c][k]
// ---------------------------------------------------------------------------
__global__ void prep_weights(const float* __restrict__ weight, const float* __restrict__ bias,
                             const float* __restrict__ w_t, const float* __restrict__ b_t,
                             const float* __restrict__ w_m, const float* __restrict__ b_m,
                             short* __restrict__ A1, short* __restrict__ A2,
                             float* __restrict__ bias32, float* __restrict__ beff32) {
  int idx = blockIdx.x * blockDim.x + threadIdx.x;
  if (idx < 7168) {                       // A1
    int j = idx & 7;
    int rest = idx >> 3;
    int l = rest & 63;
    int gm = rest >> 6;
    int g = gm % 7, mt = gm / 7;
    int o = mt * 16 + (l & 15);
    int kk = (l >> 4) * 8 + j;            // i*4+c
    float v = 0.f;
    if (o < COUT_ && kk < 28) {
      int i = kk >> 2, c = kk & 3;
      v = weight[(o * CIN_ + (g * 4 + c)) * KH_ + i];
    }
    A1[idx] = f2bf(v);
  } else if (idx < 14336) {               // A2
    int id = idx - 7168;
    int j = id & 7;
    int rest = id >> 3;
    int l = rest & 63;
    int gm = rest >> 6;
    int ks = gm % 7, mt = gm / 7;
    int o = mt * 16 + (l & 15);
    int kk = (l >> 4) * 8 + j;            // channel c
    float v = 0.f;
    if (o < COUT_ && kk < 28) {
      int f = o >> 2, cc = o & 3;
#pragma unroll
      for (int g = 0; g < DG_; ++g)
        v += w_m[f * 7 + g] * w_t[((g * 4 + cc) * COUT_ + kk) * 7 + ks];
    }
    A2[id] = f2bf(v);
  }
  if (idx < 32) {
    bias32[idx] = (idx < COUT_) ? bias[idx] : 0.f;
    float s = 0.f;
    if (idx < COUT_) {
      int f = idx >> 2, cc = idx & 3;
      s = b_m[f];
#pragma unroll
      for (int g = 0; g < DG_; ++g) s += w_m[f * 7 + g] * b_t[g * 4 + cc];
    }
    beff32[idx] = s;
  }
}

// ---------------------------------------------------------------------------
// fused MFMA kernel: one block per (b,h) row; 256 threads = 4 waves.
//  Stage 1: per g, build transposed bilinear-sample tile Bt[w][i*4+c] (bf16,
//           pitch 40) -> K=32 MFMA step. acc over 7 g.
//  Bridge:  acc+bias -> transposed tile Tt[w+3][o] (halo zeros).
//  Stage 2: folded 1x7 conv: 7 K-steps, B-frag = contiguous ds_read from Tt.
// ---------------------------------------------------------------------------
#define PITCH 40

__global__ __launch_bounds__(256)
void harmonic_mfma(const float* __restrict__ x,
                   const short* __restrict__ A1, const short* __restrict__ A2,
                   const float* __restrict__ bias32, const float* __restrict__ beff32,
                   float* __restrict__ out) {
  __shared__ short Bt[W_ * PITCH];          // 20480 B
  __shared__ short Tt[(W_ + 6) * PITCH];    // 20960 B

  const int bid = blockIdx.x;
  const int b = bid & 7;                    // XCD-aware: xcd = bid%8 = b
  const int h = bid >> 3;
  const int tid = threadIdx.x;
  const int lane = tid & 63;
  const int wv = tid >> 6;
  const int l15 = lane & 15;
  const int l4 = lane >> 4;
  const int w = tid;                        // column this thread builds

  // zero Tt halo rows {0,1,2,259,260,261} (first 64B of each row)
  if (tid < 96) {
    int rsel = tid >> 4;
    int r = (rsel < 3) ? rsel : (256 + rsel);
    ((int*)Tt)[r * (PITCH / 2) + (tid & 15)] = 0;
  }

  f32x4 acc[2][4] = {};
  const float* xb = x + (size_t)b * CIN_ * HW_ + w;

  for (int g = 0; g < DG_; ++g) {
    // ---- build Bt for this g (transposed: Bt[w*PITCH + i*4+c]) ----
#pragma unroll
    for (int i = 0; i < KH_; ++i) {
      // identical fp32 op order to reference
      float t   = ((float)(h + 1) / (float)(g + 1)) * (float)(i + 1);
      float off = ((float)(-i) + t) - (float)(h + 1);
      float yp  = (((float)h - 3.0f) + (float)i) + off;
      float y0f = floorf(yp);
      float fy  = yp - y0f;
      int y0i = (int)y0f;
      int y1i = y0i + 1;
      const bool ok0 = (y0i >= 0) && (y0i <= H_ - 1);
      const bool ok1 = (y1i >= 0) && (y1i <= H_ - 1);
      short4v pk = {0, 0, 0, 0};
      if (ok0 || ok1) {                     // wave-uniform
        float a0 = ok0 ? (1.0f - fy) : 0.0f;
        float a1 = ok1 ? fy : 0.0f;
        int y0c = y0i < 0 ? 0 : (y0i > H_ - 1 ? H_ - 1 : y0i);
        int y1c = y1i < 0 ? 0 : (y1i > H_ - 1 ? H_ - 1 : y1i);
        const float* p0 = xb + (size_t)(g * CPG_) * HW_ + y0c * W_;
        const float* p1 = xb + (size_t)(g * CPG_) * HW_ + y1c * W_;
        float v0 = a0 * p0[0 * HW_] + a1 * p1[0 * HW_];
        float v1 = a0 * p0[1 * HW_] + a1 * p1[1 * HW_];
        float v2 = a0 * p0[2 * HW_] + a1 * p1[2 * HW_];
        float v3 = a0 * p0[3 * HW_] + a1 * p1[3 * HW_];
        pk = (short4v){f2bf(v0), f2bf(v1), f2bf(v2), f2bf(v3)};
      }
      *(short4v*)&Bt[w * PITCH + i * 4] = pk;
    }
    if (g == 0) *(short4v*)&Bt[w * PITCH + 28] = (short4v){0, 0, 0, 0};
    __syncthreads();

    // ---- MFMA K-step for this g ----
    short8 a0f = *(const short8*)&A1[((0 * 7 + g) * 64 + lane) * 8];
    short8 a1f = *(const short8*)&A1[((1 * 7 + g) * 64 + lane) * 8];
#pragma unroll
    for (int nt = 0; nt < 4; ++nt) {
      int wcol = wv * 64 + nt * 16 + l15;
      short8 bf = *(const short8*)&Bt[wcol * PITCH + l4 * 8];
      acc[0][nt] = __builtin_amdgcn_mfma_f32_16x16x32_bf16(a0f, bf, acc[0][nt], 0, 0, 0);
      acc[1][nt] = __builtin_amdgcn_mfma_f32_16x16x32_bf16(a1f, bf, acc[1][nt], 0, 0, 0);
    }
    __syncthreads();
  }

  // ---- bridge: acc + bias -> Tt[wcol+3][o] (bf16) ----
#pragma unroll
  for (int mt = 0; mt < 2; ++mt) {
#pragma unroll
    for (int nt = 0; nt < 4; ++nt) {
      int wcol = wv * 64 + nt * 16 + l15;
      int o0 = mt * 16 + l4 * 4;
      f32x4 v = acc[mt][nt];
      short4v pk = {f2bf(v[0] + bias32[o0 + 0]), f2bf(v[1] + bias32[o0 + 1]),
                    f2bf(v[2] + bias32[o0 + 2]), f2bf(v[3] + bias32[o0 + 3])};
      *(short4v*)&Tt[(wcol + 3) * PITCH + o0] = pk;
    }
  }
  __syncthreads();

  // ---- stage 2: folded 1x7 conv via 7 MFMA K-steps ----
  f32x4 acc2[2][4] = {};
#pragma unroll
  for (int ks = 0; ks < 7; ++ks) {
    short8 a20 = *(const short8*)&A2[((0 * 7 + ks) * 64 + lane) * 8];
    short8 a21 = *(const short8*)&A2[((1 * 7 + ks) * 64 + lane) * 8];
#pragma unroll
    for (int nt = 0; nt < 4; ++nt) {
      int wcol = wv * 64 + nt * 16 + l15;
      short8 bf = *(const short8*)&Tt[(wcol + ks) * PITCH + l4 * 8];
      acc2[0][nt] = __builtin_amdgcn_mfma_f32_16x16x32_bf16(a20, bf, acc2[0][nt], 0, 0, 0);
      acc2[1][nt] = __builtin_amdgcn_mfma_f32_16x16x32_bf16(a21, bf, acc2[1][nt], 0, 0, 0);
    }
  }

  // ---- store ----
  float* ob = out + (size_t)b * COUT_ * HW_ + h * W_;
#pragma unroll
  for (int mt = 0; mt < 2; ++mt) {
#pragma unroll
    for (int nt = 0; nt < 4; ++nt) {
      int wcol = wv * 64 + nt * 16 + l15;
      int o0 = mt * 16 + l4 * 4;
      f32x4 v = acc2[mt][nt];
#pragma unroll
      for (int q = 0; q < 4; ++q) {
        int o = o0 + q;
        if (o < COUT_) ob[o * HW_ + wcol] = v[q] + beff32[o];
      }
    }
  }
}

extern "C" void kernel_launch(void* const* d_in, const int* in_sizes, int n_in,
                              void* d_out, int out_size, void* d_ws, size_t ws_size,
                              hipStream_t stream) {
  const float* x      = (const float*)d_in[0];
  const float* weight = (const float*)d_in[1];
  const float* bias   = (const float*)d_in[2];
  const float* w_t    = (const float*)d_in[3];
  const float* b_t    = (const float*)d_in[4];
  const float* w_m    = (const float*)d_in[5];
  const float* b_m    = (const float*)d_in[6];
  float* out = (float*)d_out;

  short* A1     = (short*)d_ws;            // 7168 bf16
  short* A2     = A1 + 7168;               // 7168 bf16
  float* bias32 = (float*)(A2 + 7168);     // 32 f32
  float* beff32 = bias32 + 32;             // 32 f32

  prep_weights<<<56, 256, 0, stream>>>(weight, bias, w_t, b_t, w_m, b_m,
                                       A1, A2, bias32, beff32);
  harmonic_mfma<<<B_ * H_, 256, 0, stream>>>(x, A1, A2, bias32, beff32, out);
}

// Round 5
// 165.619 us; speedup vs baseline: 1.9674x; 1.0970x over previous
//
#include <hip/hip_runtime.h>
#include <hip/hip_bf16.h>

#define B_    8
#define CIN_  28
#define COUT_ 28
#define H_    256
#define W_    256
#define DG_   7
#define KH_   7
#define CPG_  4
#define HW_   (H_*W_)
#define PITCH 40
#define NTAP  (DG_*KH_)   // 49

typedef short short8  __attribute__((ext_vector_type(8)));
typedef short short4v __attribute__((ext_vector_type(4)));
typedef float f32x4   __attribute__((ext_vector_type(4)));

__device__ __forceinline__ short f2bf(float f) {
  __hip_bfloat16 h = __float2bfloat16(f);   // RNE
  return *reinterpret_cast<short*>(&h);
}

__device__ __forceinline__ short8 cat8(short4v a, short4v b) {
  short8 r;
  r[0]=a[0]; r[1]=a[1]; r[2]=a[2]; r[3]=a[3];
  r[4]=b[0]; r[5]=b[1]; r[6]=b[2]; r[7]=b[3];
  return r;
}

// ---------------------------------------------------------------------------
// prep: pack stage-1 weights (A1) and folded stage-2/3 weights (A2) into
// MFMA fragment-linear order, plus padded bias vectors. (identical to the
// round-2 version that passed)
// ---------------------------------------------------------------------------
__global__ void prep_weights(const float* __restrict__ weight, const float* __restrict__ bias,
                             const float* __restrict__ w_t, const float* __restrict__ b_t,
                             const float* __restrict__ w_m, const float* __restrict__ b_m,
                             short* __restrict__ A1, short* __restrict__ A2,
                             float* __restrict__ bias32, float* __restrict__ beff32) {
  int idx = blockIdx.x * blockDim.x + threadIdx.x;
  if (idx < 7168) {                       // A1
    int j = idx & 7;
    int rest = idx >> 3;
    int l = rest & 63;
    int gm = rest >> 6;
    int g = gm % 7, mt = gm / 7;
    int o = mt * 16 + (l & 15);
    int kk = (l >> 4) * 8 + j;            // i*4+c
    float v = 0.f;
    if (o < COUT_ && kk < 28) {
      int i = kk >> 2, c = kk & 3;
      v = weight[(o * CIN_ + (g * 4 + c)) * KH_ + i];
    }
    A1[idx] = f2bf(v);
  } else if (idx < 14336) {               // A2
    int id = idx - 7168;
    int j = id & 7;
    int rest = id >> 3;
    int l = rest & 63;
    int gm = rest >> 6;
    int ks = gm % 7, mt = gm / 7;
    int o = mt * 16 + (l & 15);
    int kk = (l >> 4) * 8 + j;            // channel c
    float v = 0.f;
    if (o < COUT_ && kk < 28) {
      int f = o >> 2, cc = o & 3;
#pragma unroll
      for (int g = 0; g < DG_; ++g)
        v += w_m[f * 7 + g] * w_t[((g * 4 + cc) * COUT_ + kk) * 7 + ks];
    }
    A2[id] = f2bf(v);
  }
  if (idx < 32) {
    bias32[idx] = (idx < COUT_) ? bias[idx] : 0.f;
    float s = 0.f;
    if (idx < COUT_) {
      int f = idx >> 2, cc = idx & 3;
      s = b_m[f];
#pragma unroll
      for (int g = 0; g < DG_; ++g) s += w_m[f * 7 + g] * b_t[g * 4 + cc];
    }
    beff32[idx] = s;
  }
}

// ---------------------------------------------------------------------------
// fused MFMA kernel: one block per (b,h) row; 4 waves, wave-private stage 1.
//  - bilinear tap table computed per-wave into LDS (784 B needed; 4 private
//    copies so no barrier is required: same-wave DS ops complete in order)
//  - single 21 KB tile S used as Bt (stage 1) then Tt (stage 2)
//  - two __syncthreads total
//  - d_ws usage is the known-good 29 KB (A1/A2/bias only)
// ---------------------------------------------------------------------------
__global__ __launch_bounds__(256)
void harmonic_mfma(const float* __restrict__ x,
                   const short* __restrict__ A1, const short* __restrict__ A2,
                   const float* __restrict__ bias32, const float* __restrict__ beff32,
                   float* __restrict__ out) {
  __shared__ short S[(W_ + 6) * PITCH];     // 20960 B, Bt then Tt
  __shared__ float4 yts[4][NTAP];           // 3136 B, per-wave tap tables

  const int bid = blockIdx.x;
  const int b = bid & 7;                    // XCD-aware: all h of batch b on one XCD
  const int h = bid >> 3;
  const int tid = threadIdx.x;
  const int lane = tid & 63;
  const int wv = tid >> 6;
  const int l15 = lane & 15;
  const int l4 = lane >> 4;
  const int w = tid;

  // ---- per-wave tap table (exact reference fp32 op order) ----
  if (lane < NTAP) {
    int g = lane / 7;
    int i = lane - g * 7;
    float t   = ((float)(h + 1) / (float)(g + 1)) * (float)(i + 1);
    float off = ((float)(-i) + t) - (float)(h + 1);
    float yp  = (((float)h - 3.0f) + (float)i) + off;
    float y0f = floorf(yp);
    float fy  = yp - y0f;
    int y0i = (int)y0f;
    int y1i = y0i + 1;
    bool ok0 = (y0i >= 0) && (y0i <= H_ - 1);
    bool ok1 = (y1i >= 0) && (y1i <= H_ - 1);
    float a0 = ok0 ? (1.0f - fy) : 0.0f;
    float a1 = ok1 ? fy : 0.0f;
    int y0c = y0i < 0 ? 0 : (y0i > H_ - 1 ? H_ - 1 : y0i);
    int y1c = y1i < 0 ? 0 : (y1i > H_ - 1 ? H_ - 1 : y1i);
    float4 e;
    e.x = a0; e.y = a1;
    e.z = __int_as_float(g * CPG_ * HW_ + y0c * W_);
    e.w = __int_as_float(g * CPG_ * HW_ + y1c * W_);
    yts[wv][lane] = e;
  }
  // no barrier: readers are in the same wave; LDS ops complete in order

  f32x4 acc[2][4] = {};
  const float* xb = x + (size_t)b * CIN_ * HW_ + w;

  // zero the K-pad (shorts 28..31) of this thread's Bt row once
  *(short4v*)&S[w * PITCH + 28] = (short4v){0, 0, 0, 0};

  for (int g = 0; g < DG_; ++g) {
    // ---- build this wave's Bt cols for g (no barriers: wave-private) ----
    short4v pk[KH_];
#pragma unroll
    for (int i = 0; i < KH_; ++i) {
      float4 e = yts[wv][g * 7 + i];        // uniform LDS broadcast
      short4v p = {0, 0, 0, 0};
      if (!(e.x == 0.f && e.y == 0.f)) {    // uniform skip of dead taps
        const float* p0 = xb + __float_as_int(e.z);
        const float* p1 = xb + __float_as_int(e.w);
        float v0 = e.x * p0[0 * HW_] + e.y * p1[0 * HW_];
        float v1 = e.x * p0[1 * HW_] + e.y * p1[1 * HW_];
        float v2 = e.x * p0[2 * HW_] + e.y * p1[2 * HW_];
        float v3 = e.x * p0[3 * HW_] + e.y * p1[3 * HW_];
        p = (short4v){f2bf(v0), f2bf(v1), f2bf(v2), f2bf(v3)};
      }
      pk[i] = p;
    }
    *(short8*)&S[w * PITCH + 0]   = cat8(pk[0], pk[1]);
    *(short8*)&S[w * PITCH + 8]   = cat8(pk[2], pk[3]);
    *(short8*)&S[w * PITCH + 16]  = cat8(pk[4], pk[5]);
    *(short4v*)&S[w * PITCH + 24] = pk[6];

    // ---- MFMA K-step for this g (reads only this wave's cols) ----
    short8 a0f = *(const short8*)&A1[((0 * 7 + g) * 64 + lane) * 8];
    short8 a1f = *(const short8*)&A1[((1 * 7 + g) * 64 + lane) * 8];
#pragma unroll
    for (int nt = 0; nt < 4; ++nt) {
      int wcol = wv * 64 + nt * 16 + l15;
      short8 bf = *(const short8*)&S[wcol * PITCH + l4 * 8];
      acc[0][nt] = __builtin_amdgcn_mfma_f32_16x16x32_bf16(a0f, bf, acc[0][nt], 0, 0, 0);
      acc[1][nt] = __builtin_amdgcn_mfma_f32_16x16x32_bf16(a1f, bf, acc[1][nt], 0, 0, 0);
    }
  }

  __syncthreads();   // barrier 1: everyone done with Bt reads

  // zero Tt halo rows {0,1,2,259,260,261} (first 64B each)
  if (tid < 96) {
    int rsel = tid >> 4;
    int r = (rsel < 3) ? rsel : (256 + rsel);
    ((int*)S)[r * (PITCH / 2) + (tid & 15)] = 0;
  }

  // bridge: acc + bias -> Tt[wcol+3][o] (bf16)
#pragma unroll
  for (int mt = 0; mt < 2; ++mt) {
#pragma unroll
    for (int nt = 0; nt < 4; ++nt) {
      int wcol = wv * 64 + nt * 16 + l15;
      int o0 = mt * 16 + l4 * 4;
      f32x4 v = acc[mt][nt];
      short4v pk = {f2bf(v[0] + bias32[o0 + 0]), f2bf(v[1] + bias32[o0 + 1]),
                    f2bf(v[2] + bias32[o0 + 2]), f2bf(v[3] + bias32[o0 + 3])};
      *(short4v*)&S[(wcol + 3) * PITCH + o0] = pk;
    }
  }
  __syncthreads();   // barrier 2: Tt ready

  // ---- stage 2: folded 1x7 conv via 7 MFMA K-steps ----
  f32x4 acc2[2][4] = {};
#pragma unroll
  for (int ks = 0; ks < 7; ++ks) {
    short8 a20 = *(const short8*)&A2[((0 * 7 + ks) * 64 + lane) * 8];
    short8 a21 = *(const short8*)&A2[((1 * 7 + ks) * 64 + lane) * 8];
#pragma unroll
    for (int nt = 0; nt < 4; ++nt) {
      int wcol = wv * 64 + nt * 16 + l15;
      short8 bf = *(const short8*)&S[(wcol + ks) * PITCH + l4 * 8];
      acc2[0][nt] = __builtin_amdgcn_mfma_f32_16x16x32_bf16(a20, bf, acc2[0][nt], 0, 0, 0);
      acc2[1][nt] = __builtin_amdgcn_mfma_f32_16x16x32_bf16(a21, bf, acc2[1][nt], 0, 0, 0);
    }
  }

  // ---- store ----
  float* ob = out + (size_t)b * COUT_ * HW_ + h * W_;
#pragma unroll
  for (int mt = 0; mt < 2; ++mt) {
#pragma unroll
    for (int nt = 0; nt < 4; ++nt) {
      int wcol = wv * 64 + nt * 16 + l15;
      int o0 = mt * 16 + l4 * 4;
      f32x4 v = acc2[mt][nt];
#pragma unroll
      for (int q = 0; q < 4; ++q) {
        int o = o0 + q;
        if (o < COUT_) ob[o * HW_ + wcol] = v[q] + beff32[o];
      }
    }
  }
}

extern "C" void kernel_launch(void* const* d_in, const int* in_sizes, int n_in,
                              void* d_out, int out_size, void* d_ws, size_t ws_size,
                              hipStream_t stream) {
  const float* x      = (const float*)d_in[0];
  const float* weight = (const float*)d_in[1];
  const float* bias   = (const float*)d_in[2];
  const float* w_t    = (const float*)d_in[3];
  const float* b_t    = (const float*)d_in[4];
  const float* w_m    = (const float*)d_in[5];
  const float* b_m    = (const float*)d_in[6];
  float* out = (float*)d_out;

  short* A1     = (short*)d_ws;            // 7168 bf16
  short* A2     = A1 + 7168;               // 7168 bf16
  float* bias32 = (float*)(A2 + 7168);     // 32 f32
  float* beff32 = bias32 + 32;             // 32 f32  (total ws: 28,928 B)

  prep_weights<<<56, 256, 0, stream>>>(weight, bias, w_t, b_t, w_m, b_m,
                                       A1, A2, bias32, beff32);
  harmonic_mfma<<<B_ * H_, 256, 0, stream>>>(x, A1, A2, bias32, beff32, out);
}